// Round 1
// baseline (506.260 us; speedup 1.0000x reference)
//
#include <hip/hip_runtime.h>
#include <math.h>

// HierDSFeedForward — MI355X fp16-MFMA implementation, round 1 (baseline).
// S=4096 tokens, C=1024, H=2048, 8 experts (2 groups x 4), top-2.

#define C_DIM 1024
#define H_DIM 2048
#define S_TOK 4096

typedef _Float16 f16x8 __attribute__((ext_vector_type(8)));
typedef float f32x4 __attribute__((ext_vector_type(4)));

#define AS3(p) ((__attribute__((address_space(3))) void*)(p))
#define AS1c(p) ((const __attribute__((address_space(1))) void*)(p))

// ---------------- fp32 -> fp16 convert, 8 elems/thread ----------------
__global__ __launch_bounds__(256) void cvt_kernel(const float* __restrict__ s,
                                                  _Float16* __restrict__ d, int n8) {
  int i = blockIdx.x * 256 + threadIdx.x;
  if (i >= n8) return;
  const float4* sp = reinterpret_cast<const float4*>(s) + (size_t)i * 2;
  float4 a = sp[0], b = sp[1];
  f16x8 h;
  h[0] = (_Float16)a.x; h[1] = (_Float16)a.y; h[2] = (_Float16)a.z; h[3] = (_Float16)a.w;
  h[4] = (_Float16)b.x; h[5] = (_Float16)b.y; h[6] = (_Float16)b.z; h[7] = (_Float16)b.w;
  reinterpret_cast<f16x8*>(d)[i] = h;
}

// ---------------- gating: one wave per token, fp32 exact ----------------
__global__ __launch_bounds__(256) void gate_kernel(const float* __restrict__ x,
    const float* __restrict__ wg, const float* __restrict__ we,
    const float* __restrict__ gb, const float* __restrict__ eb,
    float* __restrict__ wse) {
  const int lane = threadIdx.x & 63;
  const int token = blockIdx.x * 4 + (threadIdx.x >> 6);
  const float* xr = x + (size_t)token * C_DIM + lane * 16;
  float xv[16];
#pragma unroll
  for (int i = 0; i < 16; i += 4) {
    float4 t = *reinterpret_cast<const float4*>(xr + i);
    xv[i] = t.x; xv[i + 1] = t.y; xv[i + 2] = t.z; xv[i + 3] = t.w;
  }
  float dots[10];
#pragma unroll
  for (int g = 0; g < 10; ++g) {
    const float* wr = (g < 2 ? wg + (size_t)g * C_DIM : we + (size_t)(g - 2) * C_DIM) + lane * 16;
    float d = 0.f;
#pragma unroll
    for (int i = 0; i < 16; i += 4) {
      float4 t = *reinterpret_cast<const float4*>(wr + i);
      d += xv[i] * t.x + xv[i + 1] * t.y + xv[i + 2] * t.z + xv[i + 3] * t.w;
    }
#pragma unroll
    for (int off = 32; off > 0; off >>= 1) d += __shfl_xor(d, off);
    dots[g] = d;
  }
  if (lane != 0) return;
  // level-1: group softmax + argmax (argmax: first max -> use >=)
  float g0 = dots[0] + gb[0], g1 = dots[1] + gb[1];
  int gidx = (g0 >= g1) ? 0 : 1;
  float gm = fmaxf(g0, g1);
  float ex0 = expf(g0 - gm), ex1 = expf(g1 - gm);
  float gprob = (gidx == 0 ? ex0 : ex1) / (ex0 + ex1);
  // level-2: softmax over the 4 experts of the chosen group
  const int base = gidx * 4;
  float el[4];
  float m = -1e30f;
#pragma unroll
  for (int j = 0; j < 4; ++j) { el[j] = dots[2 + base + j] + eb[base + j]; m = fmaxf(m, el[j]); }
  float s = 0.f;
#pragma unroll
  for (int j = 0; j < 4; ++j) { el[j] = expf(el[j] - m); s += el[j]; }
  float p[8];
#pragma unroll
  for (int e = 0; e < 8; ++e) p[e] = 0.f;
#pragma unroll
  for (int j = 0; j < 4; ++j) p[base + j] = el[j] / s * gprob;
  // top-2 (stable: strict > keeps first index on ties, matching lax.top_k)
  int i1 = 0; float v1 = -1.f;
#pragma unroll
  for (int e = 0; e < 8; ++e) if (p[e] > v1) { v1 = p[e]; i1 = e; }
  int i2 = -1; float v2 = -1.f;
#pragma unroll
  for (int e = 0; e < 8; ++e) if (e != i1 && p[e] > v2) { v2 = p[e]; i2 = e; }
#pragma unroll
  for (int e = 0; e < 8; ++e) {
    float v = (e == i1) ? v1 : ((e == i2) ? v2 : 0.f);
    wse[(size_t)token * 8 + e] = v;
  }
}

// ---------------- shared GEMM plumbing ----------------
// Tile: BM=128, BN=128, BK=64 fp16. LDS tile [128][64] with G4 XOR swizzle:
// 16B unit u of row r stored at u^(r&7)  (linear dest for global_load_lds;
// inverse swizzle applied on the per-lane GLOBAL source address — G21).
__device__ __forceinline__ void stage_tile(_Float16* lds, const _Float16* src,
                                           int ld, int tid) {
#pragma unroll
  for (int i = 0; i < 2; ++i) {
    int c = tid + i * 512;          // 16B chunk index, 1024 chunks per tile
    int row = c >> 3;               // 8 chunks (128B) per row
    int u = c & 7;
    const _Float16* g = src + (size_t)row * ld + ((u ^ (row & 7)) << 3);
    _Float16* l = lds + ((c & ~63) << 3);  // wave-uniform base; HW adds lane*16B
    __builtin_amdgcn_global_load_lds(AS1c(g), AS3(l), 16, 0, 0);
  }
}

__device__ __forceinline__ f16x8 frag_ld(const _Float16* t, int row, int u) {
  return *reinterpret_cast<const f16x8*>(t + row * 64 + ((u ^ (row & 7)) << 3));
}

// ---------------- GEMM + swiglu epilogue ----------------
// H[s, j] = silu(x @ W[j]) * (x @ W[2048+j]),  A:[S,1024] fp16, W:[4096,1024] fp16
__global__ __launch_bounds__(512) void gemm_swiglu(const _Float16* __restrict__ A,
    const _Float16* __restrict__ W, _Float16* __restrict__ H) {
  __shared__ _Float16 At[128 * 64];
  __shared__ _Float16 Ba[128 * 64];
  __shared__ _Float16 Bb[128 * 64];
  const int tid = threadIdx.x;
  const int lane = tid & 63;
  const int wid = tid >> 6;
  const int wm = wid >> 2;  // 0..1  (wave tile 64x32)
  const int wn = wid & 3;   // 0..3
  const int row0 = blockIdx.x * 128;
  const int col0 = blockIdx.y * 128;

  f32x4 accA[4][2] = {};
  f32x4 accB[4][2] = {};

  for (int kt = 0; kt < C_DIM; kt += 64) {
    stage_tile(At, A + (size_t)row0 * C_DIM + kt, C_DIM, tid);
    stage_tile(Ba, W + (size_t)col0 * C_DIM + kt, C_DIM, tid);
    stage_tile(Bb, W + (size_t)(col0 + H_DIM) * C_DIM + kt, C_DIM, tid);
    __syncthreads();  // compiler drains vmcnt before s_barrier
#pragma unroll
    for (int ks = 0; ks < 2; ++ks) {
      const int u = (ks << 2) + (lane >> 4);
      f16x8 af[4], ba[2], bb[2];
#pragma unroll
      for (int m = 0; m < 4; ++m)
        af[m] = frag_ld(At, wm * 64 + m * 16 + (lane & 15), u);
#pragma unroll
      for (int n = 0; n < 2; ++n) {
        ba[n] = frag_ld(Ba, wn * 32 + n * 16 + (lane & 15), u);
        bb[n] = frag_ld(Bb, wn * 32 + n * 16 + (lane & 15), u);
      }
#pragma unroll
      for (int m = 0; m < 4; ++m)
#pragma unroll
        for (int n = 0; n < 2; ++n) {
          accA[m][n] = __builtin_amdgcn_mfma_f32_16x16x32_f16(af[m], ba[n], accA[m][n], 0, 0, 0);
          accB[m][n] = __builtin_amdgcn_mfma_f32_16x16x32_f16(af[m], bb[n], accB[m][n], 0, 0, 0);
        }
    }
    __syncthreads();
  }
#pragma unroll
  for (int m = 0; m < 4; ++m)
#pragma unroll
    for (int n = 0; n < 2; ++n)
#pragma unroll
      for (int r = 0; r < 4; ++r) {
        int row = row0 + wm * 64 + m * 16 + ((lane >> 4) << 2) + r;
        int col = col0 + wn * 32 + n * 16 + (lane & 15);
        float a = accA[m][n][r];
        float b = accB[m][n][r];
        float hval = (a / (1.0f + expf(-a))) * b;
        H[(size_t)row * H_DIM + col] = (_Float16)hval;
      }
}

// ---------------- combine: out = H1@Woutᵀ + Σ_e wse[:,e] ⊙ (H2@W2[e]ᵀ) ----------------
__global__ __launch_bounds__(512) void gemm_combine(const _Float16* __restrict__ H1,
    const _Float16* __restrict__ H2, const _Float16* __restrict__ Wout,
    const _Float16* __restrict__ W2, const float* __restrict__ wse,
    float* __restrict__ out) {
  __shared__ _Float16 At[128 * 64];
  __shared__ _Float16 Bt[128 * 64];
  __shared__ float sse[128][8];
  const int tid = threadIdx.x;
  const int lane = tid & 63;
  const int wid = tid >> 6;
  const int wm = wid >> 2, wn = wid & 3;
  const int row0 = blockIdx.x * 128;
  const int col0 = blockIdx.y * 128;

#pragma unroll
  for (int i = 0; i < 2; ++i) {
    int idx = tid + i * 512;  // 1024 floats
    sse[idx >> 3][idx & 7] = wse[(size_t)(row0 + (idx >> 3)) * 8 + (idx & 7)];
  }

  f32x4 tot[4][2] = {};

  for (int pass = 0; pass < 9; ++pass) {
    const _Float16* Ap = (pass == 0) ? H1 : H2;
    const _Float16* Bp = (pass == 0) ? Wout : (W2 + (size_t)(pass - 1) * C_DIM * H_DIM);
    f32x4 acc[4][2] = {};
    for (int kt = 0; kt < H_DIM; kt += 64) {
      stage_tile(At, Ap + (size_t)row0 * H_DIM + kt, H_DIM, tid);
      stage_tile(Bt, Bp + (size_t)col0 * H_DIM + kt, H_DIM, tid);
      __syncthreads();
#pragma unroll
      for (int ks = 0; ks < 2; ++ks) {
        const int u = (ks << 2) + (lane >> 4);
        f16x8 af[4], bf[2];
#pragma unroll
        for (int m = 0; m < 4; ++m)
          af[m] = frag_ld(At, wm * 64 + m * 16 + (lane & 15), u);
#pragma unroll
        for (int n = 0; n < 2; ++n)
          bf[n] = frag_ld(Bt, wn * 32 + n * 16 + (lane & 15), u);
#pragma unroll
        for (int m = 0; m < 4; ++m)
#pragma unroll
          for (int n = 0; n < 2; ++n)
            acc[m][n] = __builtin_amdgcn_mfma_f32_16x16x32_f16(af[m], bf[n], acc[m][n], 0, 0, 0);
      }
      __syncthreads();
    }
    if (pass == 0) {
#pragma unroll
      for (int m = 0; m < 4; ++m)
#pragma unroll
        for (int n = 0; n < 2; ++n)
#pragma unroll
          for (int r = 0; r < 4; ++r) tot[m][n][r] += acc[m][n][r];
    } else {
      const int e = pass - 1;
#pragma unroll
      for (int m = 0; m < 4; ++m)
#pragma unroll
        for (int r = 0; r < 4; ++r) {
          const int rl = wm * 64 + m * 16 + ((lane >> 4) << 2) + r;
          const float sc = sse[rl][e];  // lanes 0-15 same addr -> LDS broadcast
#pragma unroll
          for (int n = 0; n < 2; ++n) tot[m][n][r] += sc * acc[m][n][r];
        }
    }
  }

#pragma unroll
  for (int m = 0; m < 4; ++m)
#pragma unroll
    for (int n = 0; n < 2; ++n)
#pragma unroll
      for (int r = 0; r < 4; ++r) {
        int row = row0 + wm * 64 + m * 16 + ((lane >> 4) << 2) + r;
        int col = col0 + wn * 32 + n * 16 + (lane & 15);
        out[(size_t)row * C_DIM + col] = tot[m][n][r];
      }
}

extern "C" void kernel_launch(void* const* d_in, const int* in_sizes, int n_in,
                              void* d_out, int out_size, void* d_ws, size_t ws_size,
                              hipStream_t stream) {
  const float* x     = (const float*)d_in[0];
  const float* w_in  = (const float*)d_in[1];
  const float* w_out = (const float*)d_in[2];
  const float* w1    = (const float*)d_in[3];
  const float* w2    = (const float*)d_in[4];
  const float* wg    = (const float*)d_in[5];
  const float* we    = (const float*)d_in[6];
  const float* gb    = (const float*)d_in[7];
  const float* eb    = (const float*)d_in[8];
  float* out = (float*)d_out;

  // workspace layout (~92.2 MB total)
  char* ws = (char*)d_ws;
  const size_t MB = 1u << 20;
  _Float16* xh    = (_Float16*)(ws + 0 * MB);    // 8 MB   [4096,1024]
  _Float16* winh  = (_Float16*)(ws + 8 * MB);    // 8 MB   [4096,1024]
  _Float16* w1h   = (_Float16*)(ws + 16 * MB);   // 8 MB   [4096,1024]
  _Float16* wouth = (_Float16*)(ws + 24 * MB);   // 4 MB   [1024,2048]
  _Float16* w2h   = (_Float16*)(ws + 28 * MB);   // 32 MB  [8,1024,2048]
  _Float16* H1    = (_Float16*)(ws + 60 * MB);   // 16 MB  [4096,2048]
  _Float16* H2    = (_Float16*)(ws + 76 * MB);   // 16 MB  [4096,2048]
  float*    wse   = (float*)(ws + 92 * MB);      // 128 KB [4096,8]

  auto cvt = [&](const float* s, _Float16* d, int n) {
    int n8 = n / 8;
    cvt_kernel<<<(n8 + 255) / 256, 256, 0, stream>>>(s, d, n8);
  };
  cvt(x, xh, 4096 * 1024);
  cvt(w_in, winh, 4096 * 1024);
  cvt(w1, w1h, 4096 * 1024);
  cvt(w_out, wouth, 1024 * 2048);
  cvt(w2, w2h, 8 * 1024 * 2048);

  gate_kernel<<<1024, 256, 0, stream>>>(x, wg, we, gb, eb, wse);

  gemm_swiglu<<<dim3(32, 16), 512, 0, stream>>>(xh, winh, H1);
  gemm_swiglu<<<dim3(32, 16), 512, 0, stream>>>(xh, w1h, H2);

  gemm_combine<<<dim3(32, 8), 512, 0, stream>>>(H1, H2, wouth, w2h, wse, out);
}

// Round 2
// 360.610 us; speedup vs baseline: 1.4039x; 1.4039x over previous
//
#include <hip/hip_runtime.h>
#include <math.h>

// HierDSFeedForward — round 2: sparse routed experts + fused cvt.
// S=4096 tokens, C=1024, H=2048, 8 experts (2 groups x 4), top-2.

#define C_DIM 1024
#define H_DIM 2048
#define S_TOK 4096

typedef _Float16 f16x8 __attribute__((ext_vector_type(8)));
typedef float f32x4 __attribute__((ext_vector_type(4)));

#define AS3(p) ((__attribute__((address_space(3))) void*)(p))
#define AS1c(p) ((const __attribute__((address_space(1))) void*)(p))

// ---------------- fused fp32 -> fp16 convert (all 5 tensors) ----------------
__global__ __launch_bounds__(256) void cvt_all(
    const float* __restrict__ x, const float* __restrict__ w_in,
    const float* __restrict__ w1, const float* __restrict__ w_out,
    const float* __restrict__ w2, _Float16* __restrict__ xh,
    _Float16* __restrict__ winh, _Float16* __restrict__ w1h,
    _Float16* __restrict__ wouth, _Float16* __restrict__ w2h) {
  int i = blockIdx.x * 256 + threadIdx.x;  // 8-element chunk index
  const float* s; _Float16* d; int off;
  if (i < 524288)        { s = x;     d = xh;    off = i; }
  else if (i < 1048576)  { s = w_in;  d = winh;  off = i - 524288; }
  else if (i < 1572864)  { s = w1;    d = w1h;   off = i - 1048576; }
  else if (i < 1835008)  { s = w_out; d = wouth; off = i - 1572864; }
  else                   { s = w2;    d = w2h;   off = i - 1835008; }
  const float4* sp = reinterpret_cast<const float4*>(s) + (size_t)off * 2;
  float4 a = sp[0], b = sp[1];
  f16x8 h;
  h[0] = (_Float16)a.x; h[1] = (_Float16)a.y; h[2] = (_Float16)a.z; h[3] = (_Float16)a.w;
  h[4] = (_Float16)b.x; h[5] = (_Float16)b.y; h[6] = (_Float16)b.z; h[7] = (_Float16)b.w;
  reinterpret_cast<f16x8*>(d)[off] = h;
}

// ---------------- gating: one wave per token, fp32 exact ----------------
__global__ __launch_bounds__(256) void gate_kernel(const float* __restrict__ x,
    const float* __restrict__ wg, const float* __restrict__ we,
    const float* __restrict__ gb, const float* __restrict__ eb,
    int* __restrict__ top2_e, float* __restrict__ top2_w) {
  const int lane = threadIdx.x & 63;
  const int token = blockIdx.x * 4 + (threadIdx.x >> 6);
  const float* xr = x + (size_t)token * C_DIM + lane * 16;
  float xv[16];
#pragma unroll
  for (int i = 0; i < 16; i += 4) {
    float4 t = *reinterpret_cast<const float4*>(xr + i);
    xv[i] = t.x; xv[i + 1] = t.y; xv[i + 2] = t.z; xv[i + 3] = t.w;
  }
  float dots[10];
#pragma unroll
  for (int g = 0; g < 10; ++g) {
    const float* wr = (g < 2 ? wg + (size_t)g * C_DIM : we + (size_t)(g - 2) * C_DIM) + lane * 16;
    float d = 0.f;
#pragma unroll
    for (int i = 0; i < 16; i += 4) {
      float4 t = *reinterpret_cast<const float4*>(wr + i);
      d += xv[i] * t.x + xv[i + 1] * t.y + xv[i + 2] * t.z + xv[i + 3] * t.w;
    }
#pragma unroll
    for (int off = 32; off > 0; off >>= 1) d += __shfl_xor(d, off);
    dots[g] = d;
  }
  if (lane != 0) return;
  float g0 = dots[0] + gb[0], g1 = dots[1] + gb[1];
  int gidx = (g0 >= g1) ? 0 : 1;   // argmax: first max wins
  float gm = fmaxf(g0, g1);
  float ex0 = expf(g0 - gm), ex1 = expf(g1 - gm);
  float gprob = (gidx == 0 ? ex0 : ex1) / (ex0 + ex1);
  const int base = gidx * 4;
  float el[4];
  float m = -1e30f;
#pragma unroll
  for (int j = 0; j < 4; ++j) { el[j] = dots[2 + base + j] + eb[base + j]; m = fmaxf(m, el[j]); }
  float s = 0.f;
#pragma unroll
  for (int j = 0; j < 4; ++j) { el[j] = expf(el[j] - m); s += el[j]; }
  float p[8];
#pragma unroll
  for (int e = 0; e < 8; ++e) p[e] = 0.f;
#pragma unroll
  for (int j = 0; j < 4; ++j) p[base + j] = el[j] / s * gprob;
  // stable top-2 (strict > keeps first index on ties, matching lax.top_k)
  int i1 = 0; float v1 = -1.f;
#pragma unroll
  for (int e = 0; e < 8; ++e) if (p[e] > v1) { v1 = p[e]; i1 = e; }
  int i2 = -1; float v2 = -1.f;
#pragma unroll
  for (int e = 0; e < 8; ++e) if (e != i1 && p[e] > v2) { v2 = p[e]; i2 = e; }
  top2_e[token * 2] = i1;     top2_w[token * 2] = v1;
  top2_e[token * 2 + 1] = i2; top2_w[token * 2 + 1] = v2;
}

// ---------------- count / scan / fill (single block) ----------------
__global__ __launch_bounds__(256) void scanfill(const int* __restrict__ top2_e,
    const float* __restrict__ top2_w, int* __restrict__ offs_g,
    int* __restrict__ tok_list, float* __restrict__ scale_list,
    int* __restrict__ tok2slot) {
  __shared__ int cnt[8], offs[9], cur[8];
  const int tid = threadIdx.x;
  if (tid < 8) { cnt[tid] = 0; cur[tid] = 0; }
  __syncthreads();
  for (int i = tid; i < 2 * S_TOK; i += 256) atomicAdd(&cnt[top2_e[i]], 1);
  __syncthreads();
  if (tid == 0) {
    offs[0] = 0;
    for (int e = 0; e < 8; ++e) offs[e + 1] = offs[e] + cnt[e];
    for (int e = 0; e < 9; ++e) offs_g[e] = offs[e];
  }
  __syncthreads();
  for (int i = tid; i < 2 * S_TOK; i += 256) {
    int e = top2_e[i];
    int slot = atomicAdd(&cur[e], 1);
    int g = offs[e] + slot;
    tok_list[g] = i >> 1;
    scale_list[g] = top2_w[i];
    tok2slot[i] = g;
  }
}

// ---------------- shared GEMM plumbing ----------------
// Tile [128][64] fp16 in LDS, G4 XOR swizzle: 16B unit u of row r at u^(r&7).
// Linear LDS dest for global_load_lds; inverse swizzle on the GLOBAL source.
__device__ __forceinline__ void stage_tile(_Float16* lds, const _Float16* src,
                                           int ld, int tid) {
#pragma unroll
  for (int i = 0; i < 2; ++i) {
    int c = tid + i * 512;
    int row = c >> 3;
    int u = c & 7;
    const _Float16* g = src + (size_t)row * ld + ((u ^ (row & 7)) << 3);
    _Float16* l = lds + ((c & ~63) << 3);  // wave-uniform base; HW adds lane*16B
    __builtin_amdgcn_global_load_lds(AS1c(g), AS3(l), 16, 0, 0);
  }
}

__device__ __forceinline__ f16x8 frag_ld(const _Float16* t, int row, int u) {
  return *reinterpret_cast<const f16x8*>(t + row * 64 + ((u ^ (row & 7)) << 3));
}

// ---------------- GEMM + swiglu epilogue ----------------
__global__ __launch_bounds__(512) void gemm_swiglu(const _Float16* __restrict__ A,
    const _Float16* __restrict__ W, _Float16* __restrict__ H) {
  __shared__ _Float16 At[128 * 64];
  __shared__ _Float16 Ba[128 * 64];
  __shared__ _Float16 Bb[128 * 64];
  const int tid = threadIdx.x;
  const int lane = tid & 63;
  const int wid = tid >> 6;
  const int wm = wid >> 2;
  const int wn = wid & 3;
  const int row0 = blockIdx.x * 128;
  const int col0 = blockIdx.y * 128;

  f32x4 accA[4][2] = {};
  f32x4 accB[4][2] = {};

  for (int kt = 0; kt < C_DIM; kt += 64) {
    stage_tile(At, A + (size_t)row0 * C_DIM + kt, C_DIM, tid);
    stage_tile(Ba, W + (size_t)col0 * C_DIM + kt, C_DIM, tid);
    stage_tile(Bb, W + (size_t)(col0 + H_DIM) * C_DIM + kt, C_DIM, tid);
    __syncthreads();
#pragma unroll
    for (int ks = 0; ks < 2; ++ks) {
      const int u = (ks << 2) + (lane >> 4);
      f16x8 af[4], ba[2], bb[2];
#pragma unroll
      for (int m = 0; m < 4; ++m)
        af[m] = frag_ld(At, wm * 64 + m * 16 + (lane & 15), u);
#pragma unroll
      for (int n = 0; n < 2; ++n) {
        ba[n] = frag_ld(Ba, wn * 32 + n * 16 + (lane & 15), u);
        bb[n] = frag_ld(Bb, wn * 32 + n * 16 + (lane & 15), u);
      }
#pragma unroll
      for (int m = 0; m < 4; ++m)
#pragma unroll
        for (int n = 0; n < 2; ++n) {
          accA[m][n] = __builtin_amdgcn_mfma_f32_16x16x32_f16(af[m], ba[n], accA[m][n], 0, 0, 0);
          accB[m][n] = __builtin_amdgcn_mfma_f32_16x16x32_f16(af[m], bb[n], accB[m][n], 0, 0, 0);
        }
    }
    __syncthreads();
  }
#pragma unroll
  for (int m = 0; m < 4; ++m)
#pragma unroll
    for (int n = 0; n < 2; ++n)
#pragma unroll
      for (int r = 0; r < 4; ++r) {
        int row = row0 + wm * 64 + m * 16 + ((lane >> 4) << 2) + r;
        int col = col0 + wn * 32 + n * 16 + (lane & 15);
        float a = accA[m][n][r];
        float b = accB[m][n][r];
        float hval = (a / (1.0f + expf(-a))) * b;
        H[(size_t)row * H_DIM + col] = (_Float16)hval;
      }
}

// ---------------- output GEMM: shared pass (dense) + expert passes (gathered) ----------------
// blocks 0..255:     out[rb*128.., cb*128..] = H1 @ Wout^T          (write fp32 out)
// blocks 256..2303:  routed[slot, cb*128..] = wse * (H2[tok] @ W2[e]^T)  (write fp16)
__global__ __launch_bounds__(512) void gemm_out(
    const _Float16* __restrict__ H1, const _Float16* __restrict__ H2,
    const _Float16* __restrict__ Wout, const _Float16* __restrict__ W2,
    const int* __restrict__ offs_g, const int* __restrict__ tok_list,
    const float* __restrict__ scale_list,
    float* __restrict__ out, _Float16* __restrict__ routed) {
  __shared__ _Float16 At[128 * 64];
  __shared__ _Float16 Bt[128 * 64];
  __shared__ float sse[128];
  const int tid = threadIdx.x;
  const int lane = tid & 63;
  const int wid = tid >> 6;
  const int wm = wid >> 2, wn = wid & 3;

  const int b = blockIdx.x;
  const bool shared_role = (b < 256);
  int rb, cb, offs_e = 0, n_e = 0;
  const _Float16* Bp;
  if (shared_role) {
    rb = b >> 3; cb = b & 7;
    Bp = Wout;
  } else {
    int eb = b - 256;
    int e = eb >> 8; rb = (eb >> 3) & 31; cb = eb & 7;
    offs_e = offs_g[e]; n_e = offs_g[e + 1] - offs_e;
    if (rb * 128 >= n_e) return;   // data-dependent early exit
    Bp = W2 + (size_t)e * C_DIM * H_DIM;
    if (tid < 128) {
      int lr = rb * 128 + tid;
      sse[tid] = (lr < n_e) ? scale_list[offs_e + lr] : 0.f;
    }
  }

  // per-thread A staging pointers (gathered rows are fixed across K)
  const _Float16* aptr[2];
  _Float16* ldst[2];
#pragma unroll
  for (int i = 0; i < 2; ++i) {
    int c = tid + i * 512;
    int row = c >> 3, u = c & 7;
    int swz = (u ^ (row & 7)) << 3;
    const _Float16* rowbase;
    if (shared_role) {
      rowbase = H1 + (size_t)(rb * 128 + row) * H_DIM;
    } else {
      int lr = rb * 128 + row;
      int gs = offs_e + (lr < n_e ? lr : n_e - 1);  // clamp inside segment
      rowbase = H2 + (size_t)tok_list[gs] * H_DIM;
    }
    aptr[i] = rowbase + swz;
    ldst[i] = At + ((c & ~63) << 3);
  }

  f32x4 acc[4][2] = {};
  for (int kt = 0; kt < H_DIM; kt += 64) {
#pragma unroll
    for (int i = 0; i < 2; ++i)
      __builtin_amdgcn_global_load_lds(AS1c(aptr[i] + kt), AS3(ldst[i]), 16, 0, 0);
    stage_tile(Bt, Bp + (size_t)cb * 128 * H_DIM + kt, H_DIM, tid);
    __syncthreads();
#pragma unroll
    for (int ks = 0; ks < 2; ++ks) {
      const int u = (ks << 2) + (lane >> 4);
      f16x8 af[4], bf[2];
#pragma unroll
      for (int m = 0; m < 4; ++m)
        af[m] = frag_ld(At, wm * 64 + m * 16 + (lane & 15), u);
#pragma unroll
      for (int n = 0; n < 2; ++n)
        bf[n] = frag_ld(Bt, wn * 32 + n * 16 + (lane & 15), u);
#pragma unroll
      for (int m = 0; m < 4; ++m)
#pragma unroll
        for (int n = 0; n < 2; ++n)
          acc[m][n] = __builtin_amdgcn_mfma_f32_16x16x32_f16(af[m], bf[n], acc[m][n], 0, 0, 0);
    }
    __syncthreads();
  }

#pragma unroll
  for (int m = 0; m < 4; ++m)
#pragma unroll
    for (int n = 0; n < 2; ++n)
#pragma unroll
      for (int r = 0; r < 4; ++r) {
        int rloc = wm * 64 + m * 16 + ((lane >> 4) << 2) + r;
        int col = cb * 128 + wn * 32 + n * 16 + (lane & 15);
        if (shared_role) {
          out[(size_t)(rb * 128 + rloc) * C_DIM + col] = acc[m][n][r];
        } else {
          int lr = rb * 128 + rloc;
          if (lr < n_e)
            routed[(size_t)(offs_e + lr) * C_DIM + col] =
                (_Float16)(sse[rloc] * acc[m][n][r]);
        }
      }
}

// ---------------- final gather-add: out[t] += routed[slot0] + routed[slot1] ----------------
__global__ __launch_bounds__(256) void combine_final(float* __restrict__ out,
    const _Float16* __restrict__ routed, const int* __restrict__ tok2slot) {
  const int t = blockIdx.x * 2 + (threadIdx.x >> 7);
  const int cp = (threadIdx.x & 127) << 3;
  const int s0 = tok2slot[t * 2], s1 = tok2slot[t * 2 + 1];
  f16x8 r0 = *reinterpret_cast<const f16x8*>(routed + (size_t)s0 * C_DIM + cp);
  f16x8 r1 = *reinterpret_cast<const f16x8*>(routed + (size_t)s1 * C_DIM + cp);
  float* op = out + (size_t)t * C_DIM + cp;
  float4 o0 = *reinterpret_cast<const float4*>(op);
  float4 o1 = *reinterpret_cast<const float4*>(op + 4);
  o0.x += (float)r0[0] + (float)r1[0];
  o0.y += (float)r0[1] + (float)r1[1];
  o0.z += (float)r0[2] + (float)r1[2];
  o0.w += (float)r0[3] + (float)r1[3];
  o1.x += (float)r0[4] + (float)r1[4];
  o1.y += (float)r0[5] + (float)r1[5];
  o1.z += (float)r0[6] + (float)r1[6];
  o1.w += (float)r0[7] + (float)r1[7];
  *reinterpret_cast<float4*>(op) = o0;
  *reinterpret_cast<float4*>(op + 4) = o1;
}

extern "C" void kernel_launch(void* const* d_in, const int* in_sizes, int n_in,
                              void* d_out, int out_size, void* d_ws, size_t ws_size,
                              hipStream_t stream) {
  const float* x     = (const float*)d_in[0];
  const float* w_in  = (const float*)d_in[1];
  const float* w_out = (const float*)d_in[2];
  const float* w1    = (const float*)d_in[3];
  const float* w2    = (const float*)d_in[4];
  const float* wg    = (const float*)d_in[5];
  const float* we    = (const float*)d_in[6];
  const float* gb    = (const float*)d_in[7];
  const float* eb    = (const float*)d_in[8];
  float* out = (float*)d_out;

  // workspace layout (~92.3 MB). routed (16 MB) overlays xh+winh, which are
  // dead by the time gemm_out runs (stream-ordered).
  char* ws = (char*)d_ws;
  const size_t MB = 1u << 20;
  _Float16* xh     = (_Float16*)(ws + 0 * MB);    // 8 MB  [4096,1024]
  _Float16* winh   = (_Float16*)(ws + 8 * MB);    // 8 MB  [4096,1024]
  _Float16* routed = (_Float16*)(ws + 0 * MB);    // 16 MB [8192,1024] (overlay)
  _Float16* w1h    = (_Float16*)(ws + 16 * MB);   // 8 MB  [4096,1024]
  _Float16* wouth  = (_Float16*)(ws + 24 * MB);   // 4 MB  [1024,2048]
  _Float16* w2h    = (_Float16*)(ws + 28 * MB);   // 32 MB [8,1024,2048]
  _Float16* H1     = (_Float16*)(ws + 60 * MB);   // 16 MB [4096,2048]
  _Float16* H2     = (_Float16*)(ws + 76 * MB);   // 16 MB [4096,2048]
  char* sm = ws + 92 * MB;
  int*   offs_g     = (int*)(sm);                 // 64 B (9 used)
  int*   top2_e     = (int*)(sm + 64);            // 32 KB
  float* top2_w     = (float*)(sm + 64 + 32768);  // 32 KB
  int*   tok_list   = (int*)(sm + 64 + 65536);    // 32 KB
  float* scale_list = (float*)(sm + 64 + 98304);  // 32 KB
  int*   tok2slot   = (int*)(sm + 64 + 131072);   // 32 KB

  cvt_all<<<15360, 256, 0, stream>>>(x, w_in, w1, w_out, w2,
                                     xh, winh, w1h, wouth, w2h);
  gate_kernel<<<1024, 256, 0, stream>>>(x, wg, we, gb, eb, top2_e, top2_w);
  scanfill<<<1, 256, 0, stream>>>(top2_e, top2_w, offs_g, tok_list,
                                  scale_list, tok2slot);

  gemm_swiglu<<<dim3(32, 16), 512, 0, stream>>>(xh, winh, H1);
  gemm_swiglu<<<dim3(32, 16), 512, 0, stream>>>(xh, w1h, H2);

  gemm_out<<<2304, 512, 0, stream>>>(H1, H2, wouth, w2h, offs_g, tok_list,
                                     scale_list, out, routed);
  combine_final<<<2048, 256, 0, stream>>>(out, routed, tok2slot);
}

// Round 3
// 345.167 us; speedup vs baseline: 1.4667x; 1.0447x over previous
//
#include <hip/hip_runtime.h>
#include <math.h>

// HierDSFeedForward — round 3: fused 256²/8-phase swiglu GEMM + XCD-local gemm_out.
// S=4096 tokens, C=1024, H=2048, 8 experts (2 groups x 4), top-2.

#define C_DIM 1024
#define H_DIM 2048
#define S_TOK 4096

typedef _Float16 f16x8 __attribute__((ext_vector_type(8)));
typedef float f32x4 __attribute__((ext_vector_type(4)));

#define AS3(p) ((__attribute__((address_space(3))) void*)(p))
#define AS1c(p) ((const __attribute__((address_space(1))) void*)(p))

// ---------------- fused fp32 -> fp16 convert (+ swiglu-pair row permutation) ----
// wprime[8192][1024]: rows g*32+i of each matrix = (i<16 ? a-row g*16+i
//                                                        : b-row 2048+g*16+i-16)
// so a 32-col GEMM span holds 16 a-cols then their 16 paired b-cols.
__global__ __launch_bounds__(256) void cvt_all(
    const float* __restrict__ x, const float* __restrict__ w_in,
    const float* __restrict__ w1, const float* __restrict__ w_out,
    const float* __restrict__ w2, _Float16* __restrict__ xh,
    _Float16* __restrict__ wprime, _Float16* __restrict__ wouth,
    _Float16* __restrict__ w2h) {
  int i = blockIdx.x * 256 + threadIdx.x;  // 8-element chunk index
  const float* s; _Float16* d; size_t soff, doff;
  if (i < 524288) { s = x; d = xh; soff = doff = (size_t)i; }
  else if (i < 1572864) {
    int n = i - 524288;
    int out_row = n >> 7, kc = n & 127;
    int wmat = out_row >> 12, r = out_row & 4095;
    int g = r >> 5, ii = r & 31;
    int src_row = (ii < 16) ? (g * 16 + ii) : (2048 + g * 16 + (ii - 16));
    s = wmat ? w1 : w_in; d = wprime;
    soff = (size_t)src_row * 128 + kc;
    doff = (size_t)n;
  } else if (i < 1835008) { int n = i - 1572864; s = w_out; d = wouth; soff = doff = (size_t)n; }
  else { int n = i - 1835008; s = w2; d = w2h; soff = doff = (size_t)n; }
  const float4* sp = reinterpret_cast<const float4*>(s) + soff * 2;
  float4 a = sp[0], b = sp[1];
  f16x8 h;
  h[0] = (_Float16)a.x; h[1] = (_Float16)a.y; h[2] = (_Float16)a.z; h[3] = (_Float16)a.w;
  h[4] = (_Float16)b.x; h[5] = (_Float16)b.y; h[6] = (_Float16)b.z; h[7] = (_Float16)b.w;
  reinterpret_cast<f16x8*>(d)[doff] = h;
}

// ---------------- gating: one wave per token, fp32 exact ----------------
__global__ __launch_bounds__(256) void gate_kernel(const float* __restrict__ x,
    const float* __restrict__ wg, const float* __restrict__ we,
    const float* __restrict__ gb, const float* __restrict__ eb,
    int* __restrict__ top2_e, float* __restrict__ top2_w) {
  const int lane = threadIdx.x & 63;
  const int token = blockIdx.x * 4 + (threadIdx.x >> 6);
  const float* xr = x + (size_t)token * C_DIM + lane * 16;
  float xv[16];
#pragma unroll
  for (int i = 0; i < 16; i += 4) {
    float4 t = *reinterpret_cast<const float4*>(xr + i);
    xv[i] = t.x; xv[i + 1] = t.y; xv[i + 2] = t.z; xv[i + 3] = t.w;
  }
  float dots[10];
#pragma unroll
  for (int g = 0; g < 10; ++g) {
    const float* wr = (g < 2 ? wg + (size_t)g * C_DIM : we + (size_t)(g - 2) * C_DIM) + lane * 16;
    float d = 0.f;
#pragma unroll
    for (int i = 0; i < 16; i += 4) {
      float4 t = *reinterpret_cast<const float4*>(wr + i);
      d += xv[i] * t.x + xv[i + 1] * t.y + xv[i + 2] * t.z + xv[i + 3] * t.w;
    }
#pragma unroll
    for (int off = 32; off > 0; off >>= 1) d += __shfl_xor(d, off);
    dots[g] = d;
  }
  if (lane != 0) return;
  float g0 = dots[0] + gb[0], g1 = dots[1] + gb[1];
  int gidx = (g0 >= g1) ? 0 : 1;   // argmax: first max wins
  float gm = fmaxf(g0, g1);
  float ex0 = expf(g0 - gm), ex1 = expf(g1 - gm);
  float gprob = (gidx == 0 ? ex0 : ex1) / (ex0 + ex1);
  const int base = gidx * 4;
  float el[4];
  float m = -1e30f;
#pragma unroll
  for (int jj = 0; jj < 4; ++jj) { el[jj] = dots[2 + base + jj] + eb[base + jj]; m = fmaxf(m, el[jj]); }
  float s = 0.f;
#pragma unroll
  for (int jj = 0; jj < 4; ++jj) { el[jj] = expf(el[jj] - m); s += el[jj]; }
  float p[8];
#pragma unroll
  for (int e = 0; e < 8; ++e) p[e] = 0.f;
#pragma unroll
  for (int jj = 0; jj < 4; ++jj) p[base + jj] = el[jj] / s * gprob;
  int i1 = 0; float v1 = -1.f;
#pragma unroll
  for (int e = 0; e < 8; ++e) if (p[e] > v1) { v1 = p[e]; i1 = e; }
  int i2 = -1; float v2 = -1.f;
#pragma unroll
  for (int e = 0; e < 8; ++e) if (e != i1 && p[e] > v2) { v2 = p[e]; i2 = e; }
  top2_e[token * 2] = i1;     top2_w[token * 2] = v1;
  top2_e[token * 2 + 1] = i2; top2_w[token * 2 + 1] = v2;
}

// ---------------- count / scan / fill (single block) ----------------
__global__ __launch_bounds__(256) void scanfill(const int* __restrict__ top2_e,
    const float* __restrict__ top2_w, int* __restrict__ offs_g,
    int* __restrict__ tok_list, float* __restrict__ scale_list,
    int* __restrict__ tok2slot) {
  __shared__ int cnt[8], offs[9], cur[8];
  const int tid = threadIdx.x;
  if (tid < 8) { cnt[tid] = 0; cur[tid] = 0; }
  __syncthreads();
  for (int i = tid; i < 2 * S_TOK; i += 256) atomicAdd(&cnt[top2_e[i]], 1);
  __syncthreads();
  if (tid == 0) {
    offs[0] = 0;
    for (int e = 0; e < 8; ++e) offs[e + 1] = offs[e] + cnt[e];
    for (int e = 0; e < 9; ++e) offs_g[e] = offs[e];
  }
  __syncthreads();
  for (int i = tid; i < 2 * S_TOK; i += 256) {
    int e = top2_e[i];
    int slot = atomicAdd(&cur[e], 1);
    int g = offs[e] + slot;
    tok_list[g] = i >> 1;
    scale_list[g] = top2_w[i];
    tok2slot[i] = g;
  }
}

// ---------------- shared GEMM plumbing (chunk-XOR LDS swizzle) ----------------
__device__ __forceinline__ void stage_tile(_Float16* lds_, const _Float16* src,
                                           int ld, int tid) {
#pragma unroll
  for (int i = 0; i < 2; ++i) {
    int c = tid + i * 512;
    int row = c >> 3;
    int u = c & 7;
    const _Float16* g = src + (size_t)row * ld + ((u ^ (row & 7)) << 3);
    _Float16* l = lds_ + ((c & ~63) << 3);  // wave-uniform base; HW adds lane*16B
    __builtin_amdgcn_global_load_lds(AS1c(g), AS3(l), 16, 0, 0);
  }
}

__device__ __forceinline__ f16x8 frag_ld(const _Float16* t, int row, int u) {
  return *reinterpret_cast<const f16x8*>(t + row * 64 + ((u ^ (row & 7)) << 3));
}

// ---------------- fused swiglu GEMM: 256x256 tile, BK=64, 8-phase pipeline ----
// C = x @ Wp^T with swiglu pairing baked into Wp's row order.
// LDS 128 KB: [buf0|buf1] x [A 256x64 | B 256x64] fp16, chunk-XOR swizzled.
#define BAR __builtin_amdgcn_s_barrier()
#define LGKM0 do { asm volatile("s_waitcnt lgkmcnt(0)" ::: "memory"); \
                   __builtin_amdgcn_sched_barrier(0); } while (0)
#define PRI1 __builtin_amdgcn_s_setprio(1)
#define PRI0 __builtin_amdgcn_s_setprio(0)

#define STAGEA(h_, t_) do { \
  const _Float16* s_ = aS[h_] + (size_t)(t_) * 64; \
  _Float16* d_ = lds + ((t_) & 1) * 32768 + (h_) * 8192 + grp0; \
  __builtin_amdgcn_global_load_lds(AS1c(s_), AS3(d_), 16, 0, 0); \
  __builtin_amdgcn_global_load_lds(AS1c(s_ + 65536), AS3(d_ + 4096), 16, 0, 0); \
} while (0)
#define STAGEB(h_, t_) do { \
  const _Float16* s_ = bS[h_] + (size_t)(t_) * 64; \
  _Float16* d_ = lds + ((t_) & 1) * 32768 + 16384 + (h_) * 8192 + grp0; \
  __builtin_amdgcn_global_load_lds(AS1c(s_), AS3(d_), 16, 0, 0); \
  __builtin_amdgcn_global_load_lds(AS1c(s_ + 65536), AS3(d_ + 4096), 16, 0, 0); \
} while (0)

#define LDA(MB_) do { _Pragma("unroll") for (int mm = 0; mm < 4; ++mm) \
  { _Pragma("unroll") for (int ks = 0; ks < 2; ++ks) \
    af[mm][ks] = frag_ld(At, wm * 128 + (MB_) + mm * 16 + lr, ks * 4 + lq); } } while (0)
#define LDB(DST_, CB_) do { _Pragma("unroll") for (int nn = 0; nn < 2; ++nn) \
  { _Pragma("unroll") for (int ks = 0; ks < 2; ++ks) \
    DST_[nn][ks] = frag_ld(Bt, wn * 64 + (CB_) + nn * 16 + lr, ks * 4 + lq); } } while (0)
#define QUAD(MB_, BF_, NB_) do { \
  _Pragma("unroll") for (int ks = 0; ks < 2; ++ks) \
  _Pragma("unroll") for (int mm = 0; mm < 4; ++mm) \
  _Pragma("unroll") for (int nn = 0; nn < 2; ++nn) \
    acc[(MB_) + mm][(NB_) + nn] = __builtin_amdgcn_mfma_f32_16x16x32_f16( \
        af[mm][ks], BF_[nn][ks], acc[(MB_) + mm][(NB_) + nn], 0, 0, 0); \
} while (0)

__global__ __launch_bounds__(512, 2) void gemm_fused_swiglu(
    const _Float16* __restrict__ A, const _Float16* __restrict__ Wp,
    _Float16* __restrict__ H1, _Float16* __restrict__ H2) {
  __shared__ _Float16 lds[65536];  // 128 KB
  const int tid = threadIdx.x;
  const int lane = tid & 63;
  const int wid = tid >> 6;
  const int wm = wid >> 2, wn = wid & 3;   // 2 x 4 waves; per-wave 128x64 output
  const int lr = lane & 15, lq = lane >> 4;

  // XCD-chunked block remap (512 blocks, RR dispatch: xcd = bid%8)
  const int bid = blockIdx.x;
  const int xcd = bid & 7, j = bid >> 3;
  const int nb = xcd * 4 + (j & 3);  // 4 B-panels per XCD (2 MB resident in L2)
  const int mb = j >> 2;
  const int row0 = mb * 256;
  const int colg0 = nb * 256;

  // per-thread staging geometry: chunk c=tid -> rows 0..63, c=tid+512 -> rows 64..127
  const int rA = tid >> 3, uA = tid & 7;
  const int grp0 = (tid & ~63) << 3;
  const int swz = (uA ^ (rA & 7)) << 3;
  const _Float16* aS[2];
  const _Float16* bS[2];
#pragma unroll
  for (int h = 0; h < 2; ++h) {
    aS[h] = A  + (size_t)(row0  + h * 128 + rA) * 1024 + swz;
    bS[h] = Wp + (size_t)(colg0 + h * 128 + rA) * 1024 + swz;
  }

  // prologue: stage tiles 0 and 1; wait tile 0 (8 of 16 loads)
  STAGEB(0, 0); STAGEB(1, 0); STAGEA(0, 0); STAGEA(1, 0);
  STAGEB(0, 1); STAGEB(1, 1); STAGEA(0, 1); STAGEA(1, 1);
  asm volatile("s_waitcnt vmcnt(8)" ::: "memory");
  BAR;

  f32x4 acc[8][4] = {};
  f16x8 af[4][2], bf[2][2], bf2[2][2];

  for (int t = 0; t < 16; ++t) {
    const _Float16* At = lds + (t & 1) * 32768;
    const _Float16* Bt = At + 16384;
    // q0: read A m0-3 + B n0-1; MFMA quad (0..3, 0..1)
    LDA(0); LDB(bf, 0);
    BAR; LGKM0; PRI1; QUAD(0, bf, 0); PRI0; BAR;
    // q1: read B n2-3; MFMA quad (0..3, 2..3)
    LDB(bf2, 32);
    BAR; LGKM0; PRI1; QUAD(0, bf2, 2); PRI0; BAR;
    // q2: read A m4-7; prefetch B(t+2) (B region reads retired at q1); quad (4..7, 0..1)
    LDA(64);
    if (t < 14) { STAGEB(0, t + 2); STAGEB(1, t + 2); }
    BAR; LGKM0; PRI1; QUAD(4, bf, 0); PRI0; BAR;
    // q3: prefetch A(t+2) (A region reads retired at q2); quad (4..7, 2..3)
    if (t < 14) { STAGEA(0, t + 2); STAGEA(1, t + 2); }
    BAR; PRI1; QUAD(4, bf2, 2); PRI0;
    // tile boundary: retire exactly tile t+1's 8 loads (keep t+2's in flight)
    if (t <= 13) { asm volatile("s_waitcnt vmcnt(8)" ::: "memory"); }
    else if (t == 14) { asm volatile("s_waitcnt vmcnt(0)" ::: "memory"); }
    BAR;
  }

  // epilogue: swiglu pairing — acc[m][2p] = a-col, acc[m][2p+1] = paired b-col
  _Float16* Hd = (colg0 >= 4096) ? H2 : H1;
  const int col0 = colg0 & 4095;
  const int hbase = (col0 >> 1) + wn * 32 + lr;
#pragma unroll
  for (int mm = 0; mm < 8; ++mm)
#pragma unroll
    for (int np = 0; np < 2; ++np)
#pragma unroll
      for (int r = 0; r < 4; ++r) {
        float a = acc[mm][np * 2][r];
        float b = acc[mm][np * 2 + 1][r];
        float h = (a / (1.0f + expf(-a))) * b;
        int row = row0 + wm * 128 + mm * 16 + lq * 4 + r;
        Hd[(size_t)row * H_DIM + hbase + np * 16] = (_Float16)h;
      }
}

// ---------------- output GEMM: shared pass (dense) + expert passes (gathered) --
// XCD-local remap: shared rb%8 pins A-panel sharing to one XCD; expert e pinned
// to XCD e so its 4 MB W2 slice stays L2-resident.
__global__ __launch_bounds__(512) void gemm_out(
    const _Float16* __restrict__ H1, const _Float16* __restrict__ H2,
    const _Float16* __restrict__ Wout, const _Float16* __restrict__ W2,
    const int* __restrict__ offs_g, const int* __restrict__ tok_list,
    const float* __restrict__ scale_list,
    float* __restrict__ out, _Float16* __restrict__ routed) {
  __shared__ _Float16 At[128 * 64];
  __shared__ _Float16 Bt[128 * 64];
  __shared__ float sse[128];
  const int tid = threadIdx.x;
  const int lane = tid & 63;
  const int wid = tid >> 6;
  const int wm = wid >> 2, wn = wid & 3;

  const int b = blockIdx.x;
  const bool shared_role = (b < 256);
  int rb, cb, offs_e = 0, n_e = 0;
  const _Float16* Bp;
  if (shared_role) {
    int x = b & 7, k = b >> 3;           // same rb -> same XCD
    rb = x + (k >> 3) * 8; cb = k & 7;
    Bp = Wout;
  } else {
    int bp = b - 256;
    int e = bp & 7, k = bp >> 3;         // expert e -> XCD e
    rb = k >> 3; cb = k & 7;
    offs_e = offs_g[e]; n_e = offs_g[e + 1] - offs_e;
    if (rb * 128 >= n_e) return;
    Bp = W2 + (size_t)e * C_DIM * H_DIM;
    if (tid < 128) {
      int lrr = rb * 128 + tid;
      sse[tid] = (lrr < n_e) ? scale_list[offs_e + lrr] : 0.f;
    }
  }

  const _Float16* aptr[2];
  _Float16* ldst[2];
#pragma unroll
  for (int i = 0; i < 2; ++i) {
    int c = tid + i * 512;
    int row = c >> 3, u = c & 7;
    int swz = (u ^ (row & 7)) << 3;
    const _Float16* rowbase;
    if (shared_role) {
      rowbase = H1 + (size_t)(rb * 128 + row) * H_DIM;
    } else {
      int lrr = rb * 128 + row;
      int gs = offs_e + (lrr < n_e ? lrr : n_e - 1);
      rowbase = H2 + (size_t)tok_list[gs] * H_DIM;
    }
    aptr[i] = rowbase + swz;
    ldst[i] = At + ((c & ~63) << 3);
  }

  f32x4 acc[4][2] = {};
  for (int kt = 0; kt < H_DIM; kt += 64) {
#pragma unroll
    for (int i = 0; i < 2; ++i)
      __builtin_amdgcn_global_load_lds(AS1c(aptr[i] + kt), AS3(ldst[i]), 16, 0, 0);
    stage_tile(Bt, Bp + (size_t)cb * 128 * H_DIM + kt, H_DIM, tid);
    __syncthreads();
#pragma unroll
    for (int ks = 0; ks < 2; ++ks) {
      const int u = (ks << 2) + (lane >> 4);
      f16x8 af[4], bfr[2];
#pragma unroll
      for (int m = 0; m < 4; ++m)
        af[m] = frag_ld(At, wm * 64 + m * 16 + (lane & 15), u);
#pragma unroll
      for (int n = 0; n < 2; ++n)
        bfr[n] = frag_ld(Bt, wn * 32 + n * 16 + (lane & 15), u);
#pragma unroll
      for (int m = 0; m < 4; ++m)
#pragma unroll
        for (int n = 0; n < 2; ++n)
          acc[m][n] = __builtin_amdgcn_mfma_f32_16x16x32_f16(af[m], bfr[n], acc[m][n], 0, 0, 0);
    }
    __syncthreads();
  }

#pragma unroll
  for (int m = 0; m < 4; ++m)
#pragma unroll
    for (int n = 0; n < 2; ++n)
#pragma unroll
      for (int r = 0; r < 4; ++r) {
        int rloc = wm * 64 + m * 16 + ((lane >> 4) << 2) + r;
        int col = cb * 128 + wn * 32 + n * 16 + (lane & 15);
        if (shared_role) {
          out[(size_t)(rb * 128 + rloc) * C_DIM + col] = acc[m][n][r];
        } else {
          int lrr = rb * 128 + rloc;
          if (lrr < n_e)
            routed[(size_t)(offs_e + lrr) * C_DIM + col] =
                (_Float16)(sse[rloc] * acc[m][n][r]);
        }
      }
}

// ---------------- final gather-add: out[t] += routed[slot0] + routed[slot1] ----
__global__ __launch_bounds__(256) void combine_final(float* __restrict__ out,
    const _Float16* __restrict__ routed, const int* __restrict__ tok2slot) {
  const int t = blockIdx.x * 2 + (threadIdx.x >> 7);
  const int cp = (threadIdx.x & 127) << 3;
  const int s0 = tok2slot[t * 2], s1 = tok2slot[t * 2 + 1];
  f16x8 r0 = *reinterpret_cast<const f16x8*>(routed + (size_t)s0 * C_DIM + cp);
  f16x8 r1 = *reinterpret_cast<const f16x8*>(routed + (size_t)s1 * C_DIM + cp);
  float* op = out + (size_t)t * C_DIM + cp;
  float4 o0 = *reinterpret_cast<const float4*>(op);
  float4 o1 = *reinterpret_cast<const float4*>(op + 4);
  o0.x += (float)r0[0] + (float)r1[0];
  o0.y += (float)r0[1] + (float)r1[1];
  o0.z += (float)r0[2] + (float)r1[2];
  o0.w += (float)r0[3] + (float)r1[3];
  o1.x += (float)r0[4] + (float)r1[4];
  o1.y += (float)r0[5] + (float)r1[5];
  o1.z += (float)r0[6] + (float)r1[6];
  o1.w += (float)r0[7] + (float)r1[7];
  *reinterpret_cast<float4*>(op) = o0;
  *reinterpret_cast<float4*>(op + 4) = o1;
}

extern "C" void kernel_launch(void* const* d_in, const int* in_sizes, int n_in,
                              void* d_out, int out_size, void* d_ws, size_t ws_size,
                              hipStream_t stream) {
  const float* x     = (const float*)d_in[0];
  const float* w_in  = (const float*)d_in[1];
  const float* w_out = (const float*)d_in[2];
  const float* w1    = (const float*)d_in[3];
  const float* w2    = (const float*)d_in[4];
  const float* wg    = (const float*)d_in[5];
  const float* we    = (const float*)d_in[6];
  const float* gb    = (const float*)d_in[7];
  const float* eb    = (const float*)d_in[8];
  float* out = (float*)d_out;

  // workspace (~92.3 MB). routed overlays xh+wprime head (dead by gemm_out).
  char* ws = (char*)d_ws;
  const size_t MB = 1u << 20;
  _Float16* xh     = (_Float16*)(ws + 0 * MB);    // 8 MB  [4096,1024]
  _Float16* wprime = (_Float16*)(ws + 8 * MB);    // 16 MB [8192,1024] permuted
  _Float16* routed = (_Float16*)(ws + 0 * MB);    // 16 MB [8192,1024] (overlay)
  _Float16* wouth  = (_Float16*)(ws + 24 * MB);   // 4 MB  [1024,2048]
  _Float16* w2h    = (_Float16*)(ws + 28 * MB);   // 32 MB [8,1024,2048]
  _Float16* H1     = (_Float16*)(ws + 60 * MB);   // 16 MB [4096,2048]
  _Float16* H2     = (_Float16*)(ws + 76 * MB);   // 16 MB [4096,2048]
  char* sm = ws + 92 * MB;
  int*   offs_g     = (int*)(sm);
  int*   top2_e     = (int*)(sm + 64);
  float* top2_w     = (float*)(sm + 64 + 32768);
  int*   tok_list   = (int*)(sm + 64 + 65536);
  float* scale_list = (float*)(sm + 64 + 98304);
  int*   tok2slot   = (int*)(sm + 64 + 131072);

  cvt_all<<<15360, 256, 0, stream>>>(x, w_in, w1, w_out, w2,
                                     xh, wprime, wouth, w2h);
  gate_kernel<<<1024, 256, 0, stream>>>(x, wg, we, gb, eb, top2_e, top2_w);
  scanfill<<<1, 256, 0, stream>>>(top2_e, top2_w, offs_g, tok_list,
                                  scale_list, tok2slot);

  gemm_fused_swiglu<<<512, 512, 0, stream>>>(xh, wprime, H1, H2);

  gemm_out<<<2304, 512, 0, stream>>>(H1, H2, wouth, w2h, offs_g, tok_list,
                                     scale_list, out, routed);
  combine_final<<<2048, 256, 0, stream>>>(out, routed, tok2slot);
}